// Round 5
// baseline (523.023 us; speedup 1.0000x reference)
//
#include <hip/hip_runtime.h>
#include <stdint.h>

#define NUM_NODES 17185
#define DD 6
#define FEATS (NUM_NODES * DD)   // 103110
#define BATCH 256
#define EPS 1e-5f

#define NC 256   // nodes per block (== threads, 1 node/thread)
#define BC 8     // batch rows per block (best measured)
#define NCHUNK ((NUM_NODES + NC - 1) / NC)   // 68
#define NBLOCKS (NCHUNK * (BATCH / BC))      // 2176

// Module-scope partials (d_ws unused; fills proved unconditional in R4).
// Every slot written before read within each launch -> no stale-state risk.
__device__ float g_pm[NCHUNK * 256];
__device__ float g_pc[NCHUNK];
__device__ int   g_cnt = 0;   // last-block-done counter; self-resets each launch

__global__ __launch_bounds__(NC, 6) void main_kernel(
    const float* __restrict__ data, const float* __restrict__ wb, const float* __restrict__ bb,
    const float* __restrict__ gamma, const float* __restrict__ var, const float* __restrict__ fcw,
    const float* __restrict__ beta, const float* __restrict__ mean,
    const float* __restrict__ fcb, const float* __restrict__ bnfg,
    const float* __restrict__ bnfb, const float* __restrict__ bnfm,
    const float* __restrict__ bnfv, float* __restrict__ out) {

    const int tid = threadIdx.x;
    const int n = blockIdx.x * NC + tid;
    const bool valid = (n < NUM_NODES);

    float wreg[36], bias[6], a[6];
    #pragma unroll
    for (int k = 0; k < 36; k++) wreg[k] = 0.f;
    #pragma unroll
    for (int k = 0; k < 6; k++) { bias[k] = 0.f; a[k] = 0.f; }

    float cnode = 0.f;   // per-node contribution to the BN constant (only y==0 blocks)

    if (valid) {
        const float4* wp = (const float4*)(wb + (size_t)n * 36);   // 144B stride, 16-aligned
        #pragma unroll
        for (int k = 0; k < 9; k++) {
            float4 v = wp[k];
            wreg[4*k] = v.x; wreg[4*k+1] = v.y; wreg[4*k+2] = v.z; wreg[4*k+3] = v.w;
        }
        const float2* bp = (const float2*)(bb + (size_t)n * 6);
        #pragma unroll
        for (int k = 0; k < 3; k++) { float2 v = bp[k]; bias[2*k] = v.x; bias[2*k+1] = v.y; }
        const int f0 = n * 6;
        const float2* gp = (const float2*)(gamma + f0);
        const float2* vp = (const float2*)(var + f0);
        const float2* fp = (const float2*)(fcw + f0);
        float fw[6];
        #pragma unroll
        for (int k = 0; k < 3; k++) {
            float2 g = gp[k], v = vp[k], f = fp[k];
            fw[2*k] = f.x; fw[2*k+1] = f.y;
            a[2*k]   = g.x * rsqrtf(v.x + EPS) * f.x;
            a[2*k+1] = g.y * rsqrtf(v.y + EPS) * f.y;
        }
        if (blockIdx.y == 0) {
            const float2* bep = (const float2*)(beta + f0);
            const float2* mp  = (const float2*)(mean + f0);
            #pragma unroll
            for (int k = 0; k < 3; k++) {
                float2 be = bep[k], m = mp[k];
                cnode += be.x * fw[2*k]   - m.x * a[2*k];
                cnode += be.y * fw[2*k+1] - m.y * a[2*k+1];
            }
        }
    }

    const int b0 = blockIdx.y * BC;
    float acc[BC];
    #pragma unroll
    for (int r = 0; r < BC; r++) acc[r] = 0.f;

    if (valid) {
        const float2* xbase = (const float2*)(data + (size_t)b0 * FEATS + (size_t)n * 6);
        #pragma unroll
        for (int r = 0; r < BC; r++) {
            const float2* xp = xbase + (size_t)r * (FEATS / 2);
            float2 u0 = xp[0], u1 = xp[1], u2 = xp[2];
            float x0 = u0.x, x1 = u0.y, x2 = u1.x, x3 = u1.y, x4 = u2.x, x5 = u2.y;
            #pragma unroll
            for (int o = 0; o < 6; o++) {
                float s = bias[o];
                s = fmaf(x0, wreg[o*6+0], s);
                s = fmaf(x1, wreg[o*6+1], s);
                s = fmaf(x2, wreg[o*6+2], s);
                s = fmaf(x3, wreg[o*6+3], s);
                s = fmaf(x4, wreg[o*6+4], s);
                s = fmaf(x5, wreg[o*6+5], s);
                acc[r] = fmaf(fmaxf(s, 0.f), a[o], acc[r]);
            }
        }
    }

    // Block reduction: BC independent 6-deep shuffle chains.
    __shared__ float red[4][BC];
    __shared__ float credd[4];
    __shared__ int   s_last;
    #pragma unroll
    for (int r = 0; r < BC; r++) {
        float v = acc[r];
        #pragma unroll
        for (int off = 32; off; off >>= 1) v += __shfl_down(v, off);
        if ((tid & 63) == 0) red[tid >> 6][r] = v;
    }

    if (blockIdx.y == 0) {
        float v = cnode;
        #pragma unroll
        for (int off = 32; off; off >>= 1) v += __shfl_down(v, off);
        if ((tid & 63) == 0) credd[tid >> 6] = v;
        __syncthreads();
        if (tid == 0) g_pc[blockIdx.x] = credd[0] + credd[1] + credd[2] + credd[3];
    } else {
        __syncthreads();
    }

    if (tid < BC) {
        float s = red[0][tid] + red[1][tid] + red[2][tid] + red[3][tid];
        g_pm[blockIdx.x * 256 + b0 + tid] = s;   // chunk-major
    }

    // ---- last-block-done: fold the old final_kernel into the tail ----
    __threadfence();            // release: my pm/pc writes -> device scope
    __syncthreads();            // all lanes' writes issued & fenced
    if (tid == 0) {
        int old = atomicAdd(&g_cnt, 1);          // device-scope
        s_last = (old == NBLOCKS - 1);
    }
    __syncthreads();
    if (!s_last) return;

    __threadfence();            // acquire: see all other blocks' pm/pc

    float c = (tid < NCHUNK) ? g_pc[tid] : 0.f;
    #pragma unroll
    for (int off = 32; off; off >>= 1) c += __shfl_down(c, off);
    __shared__ float fred[4];
    if ((tid & 63) == 0) fred[tid >> 6] = c;
    __syncthreads();
    const float c_sum = fred[0] + fred[1] + fred[2] + fred[3];

    float y = 0.f;
    #pragma unroll 4
    for (int ch = 0; ch < NCHUNK; ch++) y += g_pm[ch * 256 + tid];   // coalesced

    y += c_sum + fcb[0];
    float sc = bnfg[0] * rsqrtf(bnfv[0] + EPS);
    float z = (y - bnfm[0]) * sc + bnfb[0];
    out[tid] = 1.f / (1.f + expf(-z));

    if (tid == 0) g_cnt = 0;    // reset for next graph replay
}

extern "C" void kernel_launch(void* const* d_in, const int* in_sizes, int n_in,
                              void* d_out, int out_size, void* d_ws, size_t ws_size,
                              hipStream_t stream) {
    const float* data  = (const float*)d_in[0];
    const float* wb    = (const float*)d_in[1];
    const float* bb    = (const float*)d_in[2];
    const float* gamma = (const float*)d_in[3];
    const float* beta  = (const float*)d_in[4];
    const float* mean  = (const float*)d_in[5];
    const float* var   = (const float*)d_in[6];
    const float* fcw   = (const float*)d_in[7];
    const float* fcb   = (const float*)d_in[8];
    const float* bnfg  = (const float*)d_in[9];
    const float* bnfb  = (const float*)d_in[10];
    const float* bnfm  = (const float*)d_in[11];
    const float* bnfv  = (const float*)d_in[12];
    (void)d_ws; (void)ws_size;   // workspace intentionally unused (fills are unconditional)

    dim3 grid(NCHUNK, BATCH / BC);            // (68, 32) = 2176 blocks
    main_kernel<<<grid, NC, 0, stream>>>(data, wb, bb, gamma, var, fcw, beta, mean,
                                         fcb, bnfg, bnfb, bnfm, bnfv, (float*)d_out);
}